// Round 1
// baseline (855.396 us; speedup 1.0000x reference)
//
#include <hip/hip_runtime.h>
#include <math.h>

// Problem constants
// B=2, N=512, C=256, POOL=7, NC=81, IMG=1024
// M = B*N = 1024 rois, K1 = 256*49 = 12544
static constexpr int Mrois = 1024;
static constexpr int K1 = 256 * 49;

// ws layout (floats)
static constexpr size_t POOLED_OFF = 0;                          // 12,845,056
static constexpr size_t PART_OFF   = POOLED_OFF + (size_t)Mrois * K1;  // 8*1M
static constexpr size_t H1_OFF     = PART_OFF + 8ull * 1024 * 1024;
static constexpr size_t SH_OFF     = H1_OFF + 1024ull * 1024;
static constexpr size_t MW1_OFF    = SH_OFF + 1024ull * 1024;
static constexpr size_t STAT_OFF   = MW1_OFF + 81ull * 1024;

// ---------------------------------------------------------------------------
// ROI align (matches reference _roi_align / _crop_resize, batch-0 fmaps only)
// one thread per output element of pooled (1024, 256, 7, 7)
// ---------------------------------------------------------------------------
__global__ __launch_bounds__(256) void roi_pool_k(
    const float* __restrict__ p2, const float* __restrict__ p3,
    const float* __restrict__ p4, const float* __restrict__ p5,
    const float* __restrict__ rois, float* __restrict__ pooled)
{
    int idx = blockIdx.x * 256 + threadIdx.x;
    if (idx >= 1024 * 256 * 49) return;
    int px = idx % 7;
    int py = (idx / 7) % 7;
    int c  = (idx / 49) & 255;
    int n  = idx / (49 * 256);

    float4 r = ((const float4*)rois)[n];   // (x1, y1, x2, y2)
    float area = (r.w - r.y) * (r.z - r.x);
    float lf = rintf(log2f(sqrtf(area) / 224.f)) + 4.f;   // jnp.round = RNE
    float lv = fminf(fmaxf(lf, 2.f), 5.f);
    int li = (int)lv;

    const float* f; int H;
    if (li <= 2)      { f = p2; H = 256; }
    else if (li == 3) { f = p3; H = 128; }
    else if (li == 4) { f = p4; H = 64; }
    else              { f = p5; H = 32; }

    const float inv = 1.f / 1024.f;       // IMG, exact pow2
    float by1 = r.y * inv, bx1 = r.x * inv, by2 = r.w * inv, bx2 = r.z * inv;
    float Hm1 = (float)(H - 1);
    float gy = (float)py / 6.f;
    float gx = (float)px / 6.f;
    float ys = (by1 + gy * (by2 - by1)) * Hm1;
    float xs = (bx1 + gx * (bx2 - bx1)) * Hm1;
    float y0f = floorf(ys), x0f = floorf(xs);
    float ly = ys - y0f, lx = xs - x0f;
    int iy0 = (int)fminf(fmaxf(y0f,       0.f), Hm1);
    int iy1 = (int)fminf(fmaxf(y0f + 1.f, 0.f), Hm1);
    int ix0 = (int)fminf(fmaxf(x0f,       0.f), Hm1);
    int ix1 = (int)fminf(fmaxf(x0f + 1.f, 0.f), Hm1);

    const float* fc = f + (size_t)c * H * H;   // batch 0 of fmap
    float v00 = fc[iy0 * H + ix0];
    float v01 = fc[iy0 * H + ix1];
    float v10 = fc[iy1 * H + ix0];
    float v11 = fc[iy1 * H + ix1];
    float wy0 = 1.f - ly, wy1 = ly, wx0 = 1.f - lx, wx1 = lx;
    float val = v00 * wy0 * wx0 + v01 * wy0 * wx1 + v10 * wy1 * wx0 + v11 * wy1 * wx1;
    bool valid = (ys >= 0.f) && (ys <= Hm1) && (xs >= 0.f) && (xs <= Hm1);
    pooled[idx] = valid ? val : 0.f;
}

// ---------------------------------------------------------------------------
// fp32 C = A * B^T tiled GEMM with split-K partials.
// A: (M, K) row-major lda; B: (N, K) row-major ldb; Cpart[s]: (M, N).
// 256 threads; micro-tile TM x TN per thread. BK = 16.
// ---------------------------------------------------------------------------
template<int BM, int BN, int TM, int TN>
__global__ __launch_bounds__(256) void gemm_nt(
    const float* __restrict__ A, const float* __restrict__ B,
    float* __restrict__ Cpart,
    int Mm, int Nn, int lda, int ldb, int kChunk, int tilesN)
{
    constexpr int BK = 16;
    __shared__ float As[BK][BM + 4];   // +4 floats keeps 16B row alignment
    __shared__ float Bs[BK][BN + 4];

    const int tile = blockIdx.x;
    const int s    = blockIdx.y;
    const int tm0  = (tile / tilesN) * BM;
    const int tn0  = (tile % tilesN) * BN;
    const int k0   = s * kChunk;
    const int tid  = threadIdx.x;
    const int tx   = tid % (BN / TN);
    const int ty   = tid / (BN / TN);

    constexpr int AVEC = BM * BK / (256 * 4);
    constexpr int BVEC = BN * BK / (256 * 4);
    const int lrow = tid >> 2;          // 0..63
    const int lkq  = (tid & 3) * 4;     // 0,4,8,12

    float acc[TM][TN];
    #pragma unroll
    for (int i = 0; i < TM; i++)
        #pragma unroll
        for (int j = 0; j < TN; j++) acc[i][j] = 0.f;

    for (int kt = 0; kt < kChunk; kt += BK) {
        #pragma unroll
        for (int v = 0; v < AVEC; v++) {
            int row = lrow + v * 64;
            int gm = tm0 + row;
            float4 val = make_float4(0.f, 0.f, 0.f, 0.f);
            if (gm < Mm) val = *(const float4*)&A[(size_t)gm * lda + k0 + kt + lkq];
            As[lkq + 0][row] = val.x; As[lkq + 1][row] = val.y;
            As[lkq + 2][row] = val.z; As[lkq + 3][row] = val.w;
        }
        #pragma unroll
        for (int v = 0; v < BVEC; v++) {
            int row = lrow + v * 64;
            int gn = tn0 + row;
            float4 val = make_float4(0.f, 0.f, 0.f, 0.f);
            if (gn < Nn) val = *(const float4*)&B[(size_t)gn * ldb + k0 + kt + lkq];
            Bs[lkq + 0][row] = val.x; Bs[lkq + 1][row] = val.y;
            Bs[lkq + 2][row] = val.z; Bs[lkq + 3][row] = val.w;
        }
        __syncthreads();
        #pragma unroll
        for (int kk = 0; kk < BK; kk++) {
            float a[TM], b[TN];
            #pragma unroll
            for (int i = 0; i < TM; i++) a[i] = As[kk][ty * TM + i];
            #pragma unroll
            for (int j = 0; j < TN; j++) b[j] = Bs[kk][tx * TN + j];
            #pragma unroll
            for (int i = 0; i < TM; i++)
                #pragma unroll
                for (int j = 0; j < TN; j++)
                    acc[i][j] += a[i] * b[j];
        }
        __syncthreads();
    }

    float* Cs = Cpart + (size_t)s * Mm * Nn;
    #pragma unroll
    for (int i = 0; i < TM; i++) {
        int gm = tm0 + ty * TM + i;
        if (gm >= Mm) continue;
        #pragma unroll
        for (int j = 0; j < TN; j++) {
            int gn = tn0 + tx * TN + j;
            if (gn < Nn) Cs[(size_t)gm * Nn + gn] = acc[i][j];
        }
    }
}

// sum split-K partials + bias (+ optional leaky-relu), write to out
__global__ __launch_bounds__(256) void combine_k(
    const float* __restrict__ part, const float* __restrict__ bias,
    float* __restrict__ out, int MN, int Nn, int nSplit, int act)
{
    int idx = blockIdx.x * 256 + threadIdx.x;
    if (idx >= MN) return;
    float s = 0.f;
    for (int p = 0; p < nSplit; p++) s += part[(size_t)p * MN + idx];
    s += bias[idx % Nn];
    if (act == 1) s = (s >= 0.f) ? s : 0.01f * s;
    out[idx] = s;
}

// ---------------------------------------------------------------------------
// Batch-norm over axis 0 of (1024, 1024): partial sums -> finalize -> apply
// ---------------------------------------------------------------------------
__global__ __launch_bounds__(256) void bn_partial(
    const float* __restrict__ h, float* __restrict__ psum, float* __restrict__ psq)
{
    int col = blockIdx.x * 256 + threadIdx.x;   // gridDim.x = 4
    int r0  = blockIdx.y * 128;                 // gridDim.y = 8
    float s = 0.f, q = 0.f;
    for (int r = 0; r < 128; r++) {
        float v = h[(size_t)(r0 + r) * 1024 + col];
        s += v; q += v * v;
    }
    psum[blockIdx.y * 1024 + col] = s;
    psq [blockIdx.y * 1024 + col] = q;
}

__global__ __launch_bounds__(256) void bn_finalize(
    const float* __restrict__ psum, const float* __restrict__ psq,
    const float* __restrict__ g, const float* __restrict__ b,
    float* __restrict__ scale, float* __restrict__ shift)
{
    int col = blockIdx.x * 256 + threadIdx.x;   // gridDim.x = 4
    float s = 0.f, q = 0.f;
    for (int p = 0; p < 8; p++) { s += psum[p * 1024 + col]; q += psq[p * 1024 + col]; }
    float mean = s * (1.f / 1024.f);
    float var  = q * (1.f / 1024.f) - mean * mean;
    float sc = (1.f / sqrtf(var + 0.001f)) * g[col];
    scale[col] = sc;
    shift[col] = b[col] - mean * sc;
}

__global__ __launch_bounds__(256) void bn_apply_relu(
    const float* __restrict__ h, const float* __restrict__ scale,
    const float* __restrict__ shift, float* __restrict__ out)
{
    int idx = blockIdx.x * 256 + threadIdx.x;   // 1M elements
    int col = idx & 1023;
    float v = h[idx] * scale[col] + shift[col];
    out[idx] = fmaxf(v, 0.f);
}

// softmax over 81 classes, one wave per row
__global__ __launch_bounds__(64) void softmax81(
    const float* __restrict__ logits, float* __restrict__ probs)
{
    int row = blockIdx.x;
    int lane = threadIdx.x;
    const float* L = logits + (size_t)row * 81;
    float v0 = L[lane];
    float v1 = (lane + 64 < 81) ? L[lane + 64] : -INFINITY;
    float m = fmaxf(v0, v1);
    for (int o = 32; o; o >>= 1) m = fmaxf(m, __shfl_xor(m, o));
    float e0 = expf(v0 - m);
    float e1 = (lane + 64 < 81) ? expf(v1 - m) : 0.f;
    float s = e0 + e1;
    for (int o = 32; o; o >>= 1) s += __shfl_xor(s, o);
    probs[(size_t)row * 81 + lane] = e0 / s;
    if (lane + 64 < 81) probs[(size_t)row * 81 + lane + 64] = e1 / s;
}

// ---------------------------------------------------------------------------
extern "C" void kernel_launch(void* const* d_in, const int* in_sizes, int n_in,
                              void* d_out, int out_size, void* d_ws, size_t ws_size,
                              hipStream_t stream)
{
    const float* p2      = (const float*)d_in[0];
    const float* p3      = (const float*)d_in[1];
    const float* p4      = (const float*)d_in[2];
    const float* p5      = (const float*)d_in[3];
    const float* rois    = (const float*)d_in[4];
    const float* conv1_w = (const float*)d_in[5];
    const float* conv1_b = (const float*)d_in[6];
    const float* bn1_g   = (const float*)d_in[7];
    const float* bn1_b   = (const float*)d_in[8];
    const float* conv2_w = (const float*)d_in[9];
    const float* conv2_b = (const float*)d_in[10];
    const float* bn2_g   = (const float*)d_in[11];
    const float* bn2_b   = (const float*)d_in[12];
    const float* cls_w   = (const float*)d_in[13];
    const float* cls_b   = (const float*)d_in[14];
    const float* box_w   = (const float*)d_in[15];
    const float* box_b   = (const float*)d_in[16];
    const float* tf1_w   = (const float*)d_in[17];
    const float* tf1_b   = (const float*)d_in[18];
    const float* tf2_w   = (const float*)d_in[19];
    const float* tf2_b   = (const float*)d_in[20];

    float* ws  = (float*)d_ws;
    float* out = (float*)d_out;

    float* pooled = ws + POOLED_OFF;
    float* part   = ws + PART_OFF;
    float* h1     = ws + H1_OFF;
    float* sh     = ws + SH_OFF;
    float* mw1    = ws + MW1_OFF;
    float* psum   = ws + STAT_OFF;
    float* psq    = psum + 8 * 1024;
    float* scale  = psq + 8 * 1024;
    float* shift  = scale + 1024;

    // output offsets: logits 82944 | probs 82944 | bbox 331776 | mw 20736
    float* o_logits = out;
    float* o_probs  = out + 82944;
    float* o_bbox   = out + 165888;
    float* o_mw     = out + 497664;

    // 1) ROI align -> pooled (1024, 12544)
    roi_pool_k<<<50176, 256, 0, stream>>>(p2, p3, p4, p5, rois, pooled);

    // 2) conv1: (1024 x 12544) @ (1024 x 12544)^T, split-K = 8
    gemm_nt<128, 128, 8, 8><<<dim3(64, 8), 256, 0, stream>>>(
        pooled, conv1_w, part, 1024, 1024, K1, K1, K1 / 8, 8);
    combine_k<<<4096, 256, 0, stream>>>(part, conv1_b, h1, 1024 * 1024, 1024, 8, 0);

    // 3) bn1 + relu -> sh
    bn_partial<<<dim3(4, 8), 256, 0, stream>>>(h1, psum, psq);
    bn_finalize<<<4, 256, 0, stream>>>(psum, psq, bn1_g, bn1_b, scale, shift);
    bn_apply_relu<<<4096, 256, 0, stream>>>(h1, scale, shift, sh);

    // 4) conv2: 1024^3, split-K = 4
    gemm_nt<128, 128, 8, 8><<<dim3(64, 4), 256, 0, stream>>>(
        sh, conv2_w, part, 1024, 1024, 1024, 1024, 256, 8);
    combine_k<<<4096, 256, 0, stream>>>(part, conv2_b, h1, 1024 * 1024, 1024, 4, 0);

    // 5) bn2 + relu -> sh (shared)
    bn_partial<<<dim3(4, 8), 256, 0, stream>>>(h1, psum, psq);
    bn_finalize<<<4, 256, 0, stream>>>(psum, psq, bn2_g, bn2_b, scale, shift);
    bn_apply_relu<<<4096, 256, 0, stream>>>(h1, scale, shift, sh);

    // 6) logits = sh @ cls_w^T + cls_b   (M=1024, N=81, K=1024, split 4)
    gemm_nt<64, 64, 4, 4><<<dim3(32, 4), 256, 0, stream>>>(
        sh, cls_w, part, 1024, 81, 1024, 1024, 256, 2);
    combine_k<<<(82944 + 255) / 256, 256, 0, stream>>>(part, cls_b, o_logits, 82944, 81, 4, 0);

    // 7) probs = softmax(logits)
    softmax81<<<1024, 64, 0, stream>>>(o_logits, o_probs);

    // 8) bbox = sh @ box_w^T + box_b   (N=324, split 2)
    gemm_nt<64, 64, 4, 4><<<dim3(96, 2), 256, 0, stream>>>(
        sh, box_w, part, 1024, 324, 1024, 1024, 512, 6);
    combine_k<<<(331776 + 255) / 256, 256, 0, stream>>>(part, box_b, o_bbox, 331776, 324, 2, 0);

    // 9) mw1 = leaky(cls_w @ tf1_w^T + tf1_b)   (M=81, N=1024, K=1024, split 4)
    gemm_nt<64, 64, 4, 4><<<dim3(32, 4), 256, 0, stream>>>(
        cls_w, tf1_w, part, 81, 1024, 1024, 1024, 256, 16);
    combine_k<<<(82944 + 255) / 256, 256, 0, stream>>>(part, tf1_b, mw1, 82944, 1024, 4, 1);

    // 10) mw = leaky(mw1 @ tf2_w^T + tf2_b)   (M=81, N=256, K=1024, split 8)
    gemm_nt<64, 64, 4, 4><<<dim3(8, 8), 256, 0, stream>>>(
        mw1, tf2_w, part, 81, 256, 1024, 1024, 128, 4);
    combine_k<<<(20736 + 255) / 256, 256, 0, stream>>>(part, tf2_b, o_mw, 20736, 256, 8, 1);
}

// Round 2
// 558.550 us; speedup vs baseline: 1.5315x; 1.5315x over previous
//
#include <hip/hip_runtime.h>
#include <math.h>

// B=2, N=512, C=256, POOL=7, NC=81, IMG=1024 ; M = 1024 rois, K1 = 12544
static constexpr int K1 = 12544;

typedef __attribute__((ext_vector_type(8))) _Float16 f16x8;
typedef __attribute__((ext_vector_type(4))) _Float16 f16x4;
typedef __attribute__((ext_vector_type(4))) float f32x4;

// ---------------- ws layout (byte offsets) ----------------
// ph (25.69MB) | pl (25.69MB) | W1REG (25.69MB, reused) | h1 (4MB) | sh (4MB)
static constexpr size_t PH_OFF   = 0;
static constexpr size_t PL_OFF   = 25690112;
static constexpr size_t W1_OFF   = 2 * 25690112ull;           // w1h lives here during conv1
static constexpr size_t H1_OFF   = 3 * 25690112ull;           // 77,070,336
static constexpr size_t SH_OFF   = H1_OFF + 4194304;          // 81,264,640
// overlay inside W1 region, used only AFTER conv1 gemm completes:
static constexpr size_t W2H_OFF  = W1_OFF;                    // 2MB
static constexpr size_t SHH_OFF  = W1_OFF + 2097152;          // 2MB
static constexpr size_t SHL_OFF  = W1_OFF + 2 * 2097152;      // 2MB
static constexpr size_t PART_OFF = W1_OFF + 3 * 2097152;      // ~2.7MB max
static constexpr size_t MW1_OFF  = W1_OFF + 9437184;          // 0.34MB
static constexpr size_t STAT_OFF = W1_OFF + 10485760;         // ~80KB

// ---------------------------------------------------------------------------
// async global->LDS helper (width 16)
// ---------------------------------------------------------------------------
__device__ __forceinline__ void gload16(const void* g, void* l) {
    __builtin_amdgcn_global_load_lds(
        (const __attribute__((address_space(1))) void*)g,
        (__attribute__((address_space(3))) void*)l, 16, 0, 0);
}

// ---------------------------------------------------------------------------
// ROI align -> pooled written directly as fp16 hi + fp16 lo residual
// ---------------------------------------------------------------------------
__global__ __launch_bounds__(256) void roi_pool16_k(
    const float* __restrict__ p2, const float* __restrict__ p3,
    const float* __restrict__ p4, const float* __restrict__ p5,
    const float* __restrict__ rois,
    _Float16* __restrict__ ph, _Float16* __restrict__ pl)
{
    int idx = blockIdx.x * 256 + threadIdx.x;
    if (idx >= 1024 * 256 * 49) return;
    int px = idx % 7;
    int py = (idx / 7) % 7;
    int c  = (idx / 49) & 255;
    int n  = idx / (49 * 256);

    float4 r = ((const float4*)rois)[n];   // (x1, y1, x2, y2)
    float area = (r.w - r.y) * (r.z - r.x);
    float lf = rintf(log2f(sqrtf(area) / 224.f)) + 4.f;
    float lv = fminf(fmaxf(lf, 2.f), 5.f);
    int li = (int)lv;

    const float* f; int H;
    if (li <= 2)      { f = p2; H = 256; }
    else if (li == 3) { f = p3; H = 128; }
    else if (li == 4) { f = p4; H = 64; }
    else              { f = p5; H = 32; }

    const float inv = 1.f / 1024.f;
    float by1 = r.y * inv, bx1 = r.x * inv, by2 = r.w * inv, bx2 = r.z * inv;
    float Hm1 = (float)(H - 1);
    float gy = (float)py / 6.f;
    float gx = (float)px / 6.f;
    float ys = (by1 + gy * (by2 - by1)) * Hm1;
    float xs = (bx1 + gx * (bx2 - bx1)) * Hm1;
    float y0f = floorf(ys), x0f = floorf(xs);
    float ly = ys - y0f, lx = xs - x0f;
    int iy0 = (int)fminf(fmaxf(y0f,       0.f), Hm1);
    int iy1 = (int)fminf(fmaxf(y0f + 1.f, 0.f), Hm1);
    int ix0 = (int)fminf(fmaxf(x0f,       0.f), Hm1);
    int ix1 = (int)fminf(fmaxf(x0f + 1.f, 0.f), Hm1);

    const float* fc = f + (size_t)c * H * H;
    float v00 = fc[iy0 * H + ix0];
    float v01 = fc[iy0 * H + ix1];
    float v10 = fc[iy1 * H + ix0];
    float v11 = fc[iy1 * H + ix1];
    float wy0 = 1.f - ly, wy1 = ly, wx0 = 1.f - lx, wx1 = lx;
    float val = v00 * wy0 * wx0 + v01 * wy0 * wx1 + v10 * wy1 * wx0 + v11 * wy1 * wx1;
    bool valid = (ys >= 0.f) && (ys <= Hm1) && (xs >= 0.f) && (xs <= Hm1);
    val = valid ? val : 0.f;
    _Float16 hi = (_Float16)val;
    ph[idx] = hi;
    pl[idx] = (_Float16)(val - (float)hi);
}

// fp32 -> fp16, 4 elements/thread
__global__ __launch_bounds__(256) void cvt16_k(
    const float* __restrict__ src, _Float16* __restrict__ dst, int n4)
{
    int i = blockIdx.x * 256 + threadIdx.x;
    if (i >= n4) return;
    float4 v = ((const float4*)src)[i];
    f16x4 h;
    h.x = (_Float16)v.x; h.y = (_Float16)v.y;
    h.z = (_Float16)v.z; h.w = (_Float16)v.w;
    ((f16x4*)dst)[i] = h;
}

// out[idx] = bias[idx % 1024]
__global__ __launch_bounds__(256) void init_bias_k(
    const float* __restrict__ bias, float* __restrict__ out)
{
    int idx = blockIdx.x * 256 + threadIdx.x;
    out[idx] = bias[idx & 1023];
}

// ---------------------------------------------------------------------------
// fp16 MFMA GEMM: C += (Ah + Al) * Bh^T   (2 MFMAs per fragment pair)
// A: (M,K) fp16 hi/lo row-major; B: (N,K) fp16 row-major; C fp32 (M,N) atomic.
// 128x128 tile, 256 thr = 4 waves (2x2 of 64x64), BK=32, split-K over grid.y.
// M, N must be multiples of 128 (1024 here).
// ---------------------------------------------------------------------------
__global__ __launch_bounds__(256) void gemm16_nt(
    const _Float16* __restrict__ Ah, const _Float16* __restrict__ Al,
    const _Float16* __restrict__ Bh, float* __restrict__ C,
    int Nn, int lda, int ldb, int kChunk, int tilesN)
{
    __shared__ _Float16 sAh[128][32];
    __shared__ _Float16 sAl[128][32];
    __shared__ _Float16 sBh[128][32];

    const int tid  = threadIdx.x;
    const int lane = tid & 63;
    const int wave = tid >> 6;
    const int tm0  = (blockIdx.x / tilesN) * 128;
    const int tn0  = (blockIdx.x % tilesN) * 128;
    const int k0   = blockIdx.y * kChunk;

    const int wm = (wave >> 1) * 64;   // wave row offset in tile
    const int wn = (wave & 1) * 64;    // wave col offset in tile

    // staging: this wave stages rows [wave*32, wave*32+32) of each LDS tile
    const int srow = wave * 32 + (lane >> 2);   // +0 and +16
    const int skh  = (lane & 3) * 8;            // halfs within 64B row

    f32x4 acc[4][4];
    #pragma unroll
    for (int i = 0; i < 4; i++)
        #pragma unroll
        for (int j = 0; j < 4; j++) acc[i][j] = (f32x4){0.f, 0.f, 0.f, 0.f};

    const int mrow = wm + (lane & 15);
    const int ncol = wn + (lane & 15);
    const int koff = (lane >> 4) * 8;

    for (int kt = 0; kt < kChunk; kt += 32) {
        const size_t ka = (size_t)(tm0 + srow) * lda + k0 + kt + skh;
        const size_t kb = (size_t)(tn0 + srow) * ldb + k0 + kt + skh;
        gload16(Ah + ka,            &sAh[wave * 32][0]);
        gload16(Ah + ka + 16 * lda, &sAh[wave * 32 + 16][0]);
        gload16(Al + ka,            &sAl[wave * 32][0]);
        gload16(Al + ka + 16 * lda, &sAl[wave * 32 + 16][0]);
        gload16(Bh + kb,            &sBh[wave * 32][0]);
        gload16(Bh + kb + 16 * ldb, &sBh[wave * 32 + 16][0]);
        __syncthreads();

        f16x8 fa[4], fl[4], fb[4];
        #pragma unroll
        for (int t = 0; t < 4; t++) {
            fa[t] = *(const f16x8*)&sAh[mrow + t * 16][koff];
            fl[t] = *(const f16x8*)&sAl[mrow + t * 16][koff];
            fb[t] = *(const f16x8*)&sBh[ncol + t * 16][koff];
        }
        #pragma unroll
        for (int i = 0; i < 4; i++)
            #pragma unroll
            for (int j = 0; j < 4; j++) {
                acc[i][j] = __builtin_amdgcn_mfma_f32_16x16x32_f16(fa[i], fb[j], acc[i][j], 0, 0, 0);
                acc[i][j] = __builtin_amdgcn_mfma_f32_16x16x32_f16(fl[i], fb[j], acc[i][j], 0, 0, 0);
            }
        __syncthreads();
    }

    // C/D layout: col = lane&15, row = (lane>>4)*4 + reg
    const int crow = tm0 + wm + (lane >> 4) * 4;
    const int ccol = tn0 + wn + (lane & 15);
    #pragma unroll
    for (int i = 0; i < 4; i++)
        #pragma unroll
        for (int j = 0; j < 4; j++) {
            float* cp = C + (size_t)(crow + i * 16) * Nn + (ccol + j * 16);
            #pragma unroll
            for (int rg = 0; rg < 4; rg++)
                unsafeAtomicAdd(cp + (size_t)rg * Nn, acc[i][j][rg]);
        }
}

// ---------------------------------------------------------------------------
// fp32 tiled GEMM (small matrices): C = A * B^T, split-K partials
// ---------------------------------------------------------------------------
template<int BM, int BN, int TM, int TN>
__global__ __launch_bounds__(256) void gemm_nt(
    const float* __restrict__ A, const float* __restrict__ B,
    float* __restrict__ Cpart,
    int Mm, int Nn, int lda, int ldb, int kChunk, int tilesN)
{
    constexpr int BK = 16;
    __shared__ float As[BK][BM + 4];
    __shared__ float Bs[BK][BN + 4];

    const int tile = blockIdx.x;
    const int s    = blockIdx.y;
    const int tm0  = (tile / tilesN) * BM;
    const int tn0  = (tile % tilesN) * BN;
    const int k0   = s * kChunk;
    const int tid  = threadIdx.x;
    const int tx   = tid % (BN / TN);
    const int ty   = tid / (BN / TN);

    constexpr int AVEC = BM * BK / (256 * 4);
    constexpr int BVEC = BN * BK / (256 * 4);
    const int lrow = tid >> 2;
    const int lkq  = (tid & 3) * 4;

    float acc[TM][TN];
    #pragma unroll
    for (int i = 0; i < TM; i++)
        #pragma unroll
        for (int j = 0; j < TN; j++) acc[i][j] = 0.f;

    for (int kt = 0; kt < kChunk; kt += BK) {
        #pragma unroll
        for (int v = 0; v < AVEC; v++) {
            int row = lrow + v * 64;
            int gm = tm0 + row;
            float4 val = make_float4(0.f, 0.f, 0.f, 0.f);
            if (gm < Mm) val = *(const float4*)&A[(size_t)gm * lda + k0 + kt + lkq];
            As[lkq + 0][row] = val.x; As[lkq + 1][row] = val.y;
            As[lkq + 2][row] = val.z; As[lkq + 3][row] = val.w;
        }
        #pragma unroll
        for (int v = 0; v < BVEC; v++) {
            int row = lrow + v * 64;
            int gn = tn0 + row;
            float4 val = make_float4(0.f, 0.f, 0.f, 0.f);
            if (gn < Nn) val = *(const float4*)&B[(size_t)gn * ldb + k0 + kt + lkq];
            Bs[lkq + 0][row] = val.x; Bs[lkq + 1][row] = val.y;
            Bs[lkq + 2][row] = val.z; Bs[lkq + 3][row] = val.w;
        }
        __syncthreads();
        #pragma unroll
        for (int kk = 0; kk < BK; kk++) {
            float a[TM], b[TN];
            #pragma unroll
            for (int i = 0; i < TM; i++) a[i] = As[kk][ty * TM + i];
            #pragma unroll
            for (int j = 0; j < TN; j++) b[j] = Bs[kk][tx * TN + j];
            #pragma unroll
            for (int i = 0; i < TM; i++)
                #pragma unroll
                for (int j = 0; j < TN; j++)
                    acc[i][j] += a[i] * b[j];
        }
        __syncthreads();
    }

    float* Cs = Cpart + (size_t)s * Mm * Nn;
    #pragma unroll
    for (int i = 0; i < TM; i++) {
        int gm = tm0 + ty * TM + i;
        if (gm >= Mm) continue;
        #pragma unroll
        for (int j = 0; j < TN; j++) {
            int gn = tn0 + tx * TN + j;
            if (gn < Nn) Cs[(size_t)gm * Nn + gn] = acc[i][j];
        }
    }
}

__global__ __launch_bounds__(256) void combine_k(
    const float* __restrict__ part, const float* __restrict__ bias,
    float* __restrict__ out, int MN, int Nn, int nSplit, int act)
{
    int idx = blockIdx.x * 256 + threadIdx.x;
    if (idx >= MN) return;
    float s = 0.f;
    for (int p = 0; p < nSplit; p++) s += part[(size_t)p * MN + idx];
    s += bias[idx % Nn];
    if (act == 1) s = (s >= 0.f) ? s : 0.01f * s;
    out[idx] = s;
}

// ---------------------------------------------------------------------------
// batch-norm over axis 0 of (1024, 1024)
// ---------------------------------------------------------------------------
__global__ __launch_bounds__(256) void bn_partial(
    const float* __restrict__ h, float* __restrict__ psum, float* __restrict__ psq)
{
    int col = blockIdx.x * 256 + threadIdx.x;
    int r0  = blockIdx.y * 128;
    float s = 0.f, q = 0.f;
    for (int r = 0; r < 128; r++) {
        float v = h[(size_t)(r0 + r) * 1024 + col];
        s += v; q += v * v;
    }
    psum[blockIdx.y * 1024 + col] = s;
    psq [blockIdx.y * 1024 + col] = q;
}

__global__ __launch_bounds__(256) void bn_finalize(
    const float* __restrict__ psum, const float* __restrict__ psq,
    const float* __restrict__ g, const float* __restrict__ b,
    float* __restrict__ scale, float* __restrict__ shift)
{
    int col = blockIdx.x * 256 + threadIdx.x;
    float s = 0.f, q = 0.f;
    for (int p = 0; p < 8; p++) { s += psum[p * 1024 + col]; q += psq[p * 1024 + col]; }
    float mean = s * (1.f / 1024.f);
    float var  = q * (1.f / 1024.f) - mean * mean;
    float sc = (1.f / sqrtf(var + 0.001f)) * g[col];
    scale[col] = sc;
    shift[col] = b[col] - mean * sc;
}

// bn+relu, output fp16 hi/lo (conv2 input path)
__global__ __launch_bounds__(256) void bn_apply_relu_split16(
    const float* __restrict__ h, const float* __restrict__ scale,
    const float* __restrict__ shift, _Float16* __restrict__ oh,
    _Float16* __restrict__ ol)
{
    int idx = blockIdx.x * 256 + threadIdx.x;
    int col = idx & 1023;
    float v = fmaxf(h[idx] * scale[col] + shift[col], 0.f);
    _Float16 hi = (_Float16)v;
    oh[idx] = hi;
    ol[idx] = (_Float16)(v - (float)hi);
}

// bn+relu, output fp32 (cls/box input path)
__global__ __launch_bounds__(256) void bn_apply_relu_f32(
    const float* __restrict__ h, const float* __restrict__ scale,
    const float* __restrict__ shift, float* __restrict__ out)
{
    int idx = blockIdx.x * 256 + threadIdx.x;
    int col = idx & 1023;
    out[idx] = fmaxf(h[idx] * scale[col] + shift[col], 0.f);
}

__global__ __launch_bounds__(64) void softmax81(
    const float* __restrict__ logits, float* __restrict__ probs)
{
    int row = blockIdx.x;
    int lane = threadIdx.x;
    const float* L = logits + (size_t)row * 81;
    float v0 = L[lane];
    float v1 = (lane + 64 < 81) ? L[lane + 64] : -INFINITY;
    float m = fmaxf(v0, v1);
    for (int o = 32; o; o >>= 1) m = fmaxf(m, __shfl_xor(m, o));
    float e0 = expf(v0 - m);
    float e1 = (lane + 64 < 81) ? expf(v1 - m) : 0.f;
    float s = e0 + e1;
    for (int o = 32; o; o >>= 1) s += __shfl_xor(s, o);
    probs[(size_t)row * 81 + lane] = e0 / s;
    if (lane + 64 < 81) probs[(size_t)row * 81 + lane + 64] = e1 / s;
}

// ---------------------------------------------------------------------------
extern "C" void kernel_launch(void* const* d_in, const int* in_sizes, int n_in,
                              void* d_out, int out_size, void* d_ws, size_t ws_size,
                              hipStream_t stream)
{
    const float* p2      = (const float*)d_in[0];
    const float* p3      = (const float*)d_in[1];
    const float* p4      = (const float*)d_in[2];
    const float* p5      = (const float*)d_in[3];
    const float* rois    = (const float*)d_in[4];
    const float* conv1_w = (const float*)d_in[5];
    const float* conv1_b = (const float*)d_in[6];
    const float* bn1_g   = (const float*)d_in[7];
    const float* bn1_b   = (const float*)d_in[8];
    const float* conv2_w = (const float*)d_in[9];
    const float* conv2_b = (const float*)d_in[10];
    const float* bn2_g   = (const float*)d_in[11];
    const float* bn2_b   = (const float*)d_in[12];
    const float* cls_w   = (const float*)d_in[13];
    const float* cls_b   = (const float*)d_in[14];
    const float* box_w   = (const float*)d_in[15];
    const float* box_b   = (const float*)d_in[16];
    const float* tf1_w   = (const float*)d_in[17];
    const float* tf1_b   = (const float*)d_in[18];
    const float* tf2_w   = (const float*)d_in[19];
    const float* tf2_b   = (const float*)d_in[20];

    char* wsb = (char*)d_ws;
    float* out = (float*)d_out;

    _Float16* ph   = (_Float16*)(wsb + PH_OFF);
    _Float16* pl   = (_Float16*)(wsb + PL_OFF);
    _Float16* w1h  = (_Float16*)(wsb + W1_OFF);
    _Float16* w2h  = (_Float16*)(wsb + W2H_OFF);
    _Float16* shh  = (_Float16*)(wsb + SHH_OFF);
    _Float16* shl  = (_Float16*)(wsb + SHL_OFF);
    float* h1      = (float*)(wsb + H1_OFF);
    float* sh      = (float*)(wsb + SH_OFF);
    float* part    = (float*)(wsb + PART_OFF);
    float* mw1     = (float*)(wsb + MW1_OFF);
    float* psum    = (float*)(wsb + STAT_OFF);
    float* psq     = psum + 8 * 1024;
    float* scale   = psq + 8 * 1024;
    float* shift   = scale + 1024;

    float* o_logits = out;
    float* o_probs  = out + 82944;
    float* o_bbox   = out + 165888;
    float* o_mw     = out + 497664;

    // 1) w1 -> fp16  (12544*1024 = 12.845M elems, /4 per thread)
    cvt16_k<<<12544, 256, 0, stream>>>(conv1_w, w1h, 12544 * 1024 / 4);

    // 2) ROI align -> ph/pl (1024, 12544)
    roi_pool16_k<<<50176, 256, 0, stream>>>(p2, p3, p4, p5, rois, ph, pl);

    // 3) conv1: h1 = bias ; h1 += (ph+pl) @ w1h^T   (split-K=8, atomics)
    init_bias_k<<<4096, 256, 0, stream>>>(conv1_b, h1);
    gemm16_nt<<<dim3(64, 8), 256, 0, stream>>>(ph, pl, w1h, h1, 1024, K1, K1, K1 / 8, 8);

    // 4) bn1 + relu -> shh/shl (fp16 hi/lo) ; also prep w2
    bn_partial<<<dim3(4, 8), 256, 0, stream>>>(h1, psum, psq);
    bn_finalize<<<4, 256, 0, stream>>>(psum, psq, bn1_g, bn1_b, scale, shift);
    bn_apply_relu_split16<<<4096, 256, 0, stream>>>(h1, scale, shift, shh, shl);
    cvt16_k<<<1024, 256, 0, stream>>>(conv2_w, w2h, 1024 * 1024 / 4);

    // 5) conv2: h1 = bias ; h1 += (shh+shl) @ w2h^T  (split-K=4)
    init_bias_k<<<4096, 256, 0, stream>>>(conv2_b, h1);
    gemm16_nt<<<dim3(64, 4), 256, 0, stream>>>(shh, shl, w2h, h1, 1024, 1024, 1024, 256, 8);

    // 6) bn2 + relu -> sh (fp32)
    bn_partial<<<dim3(4, 8), 256, 0, stream>>>(h1, psum, psq);
    bn_finalize<<<4, 256, 0, stream>>>(psum, psq, bn2_g, bn2_b, scale, shift);
    bn_apply_relu_f32<<<4096, 256, 0, stream>>>(h1, scale, shift, sh);

    // 7) logits = sh @ cls_w^T + cls_b   (M=1024, N=81, K=1024, split 4)
    gemm_nt<64, 64, 4, 4><<<dim3(32, 4), 256, 0, stream>>>(
        sh, cls_w, part, 1024, 81, 1024, 1024, 256, 2);
    combine_k<<<(82944 + 255) / 256, 256, 0, stream>>>(part, cls_b, o_logits, 82944, 81, 4, 0);

    // 8) probs
    softmax81<<<1024, 64, 0, stream>>>(o_logits, o_probs);

    // 9) bbox = sh @ box_w^T + box_b   (N=324, split 2)
    gemm_nt<64, 64, 4, 4><<<dim3(96, 2), 256, 0, stream>>>(
        sh, box_w, part, 1024, 324, 1024, 1024, 512, 6);
    combine_k<<<(331776 + 255) / 256, 256, 0, stream>>>(part, box_b, o_bbox, 331776, 324, 2, 0);

    // 10) mw1 = leaky(cls_w @ tf1_w^T + tf1_b)
    gemm_nt<64, 64, 4, 4><<<dim3(32, 4), 256, 0, stream>>>(
        cls_w, tf1_w, part, 81, 1024, 1024, 1024, 256, 16);
    combine_k<<<(82944 + 255) / 256, 256, 0, stream>>>(part, tf1_b, mw1, 82944, 1024, 4, 1);

    // 11) mw = leaky(mw1 @ tf2_w^T + tf2_b)
    gemm_nt<64, 64, 4, 4><<<dim3(8, 8), 256, 0, stream>>>(
        mw1, tf2_w, part, 81, 256, 1024, 1024, 128, 4);
    combine_k<<<(20736 + 255) / 256, 256, 0, stream>>>(part, tf2_b, o_mw, 20736, 256, 8, 1);
}

// Round 3
// 512.739 us; speedup vs baseline: 1.6683x; 1.0893x over previous
//
#include <hip/hip_runtime.h>
#include <math.h>

// B=2, N=512, C=256, POOL=7, NC=81, IMG=1024 ; M = 1024 rois, K1 = 12544
static constexpr int K1 = 12544;

typedef __attribute__((ext_vector_type(8))) _Float16 f16x8;
typedef __attribute__((ext_vector_type(4))) _Float16 f16x4;
typedef __attribute__((ext_vector_type(4))) float f32x4;

// ---------------- ws layout (byte offsets) ----------------
static constexpr size_t PH_OFF   = 0;                        // 25.69 MB (1024x12544 fp16)
static constexpr size_t W1_OFF   = 25690112;                 // 25.69 MB
static constexpr size_t H1_OFF   = 51380224;                 // 4 MB fp32
static constexpr size_t S1H_OFF  = 55574528;                 // 2 MB fp16
static constexpr size_t S2H_OFF  = 57671680;                 // 2 MB fp16
static constexpr size_t W2H_OFF  = 59768832;                 // 2 MB fp16
static constexpr size_t WCAT_OFF = 61865984;                 // 1 MB fp16 (512x1024, rows 0..404 used)
static constexpr size_t HCAT_OFF = 62914560;                 // 2 MB fp32 (1024x512)
static constexpr size_t MW1_OFF  = 65011712;                 // 0.33 MB
static constexpr size_t PART_OFF = 65343488;                 // 2 MB reserve
static constexpr size_t STAT_OFF = 67440640;                 // bn stats

// ---------------------------------------------------------------------------
__device__ __forceinline__ void gload16(const void* g, void* l) {
    __builtin_amdgcn_global_load_lds(
        (const __attribute__((address_space(1))) void*)g,
        (__attribute__((address_space(3))) void*)l, 16, 0, 0);
}

// ---------------------------------------------------------------------------
// ROI align -> pooled fp16 (hi only)
// ---------------------------------------------------------------------------
__global__ __launch_bounds__(256) void roi_pool16_k(
    const float* __restrict__ p2, const float* __restrict__ p3,
    const float* __restrict__ p4, const float* __restrict__ p5,
    const float* __restrict__ rois, _Float16* __restrict__ ph)
{
    int idx = blockIdx.x * 256 + threadIdx.x;
    if (idx >= 1024 * 256 * 49) return;
    int px = idx % 7;
    int py = (idx / 7) % 7;
    int c  = (idx / 49) & 255;
    int n  = idx / (49 * 256);

    float4 r = ((const float4*)rois)[n];   // (x1, y1, x2, y2)
    float area = (r.w - r.y) * (r.z - r.x);
    float lf = rintf(log2f(sqrtf(area) / 224.f)) + 4.f;
    float lv = fminf(fmaxf(lf, 2.f), 5.f);
    int li = (int)lv;

    const float* f; int H;
    if (li <= 2)      { f = p2; H = 256; }
    else if (li == 3) { f = p3; H = 128; }
    else if (li == 4) { f = p4; H = 64; }
    else              { f = p5; H = 32; }

    const float inv = 1.f / 1024.f;
    float by1 = r.y * inv, bx1 = r.x * inv, by2 = r.w * inv, bx2 = r.z * inv;
    float Hm1 = (float)(H - 1);
    float gy = (float)py / 6.f;
    float gx = (float)px / 6.f;
    float ys = (by1 + gy * (by2 - by1)) * Hm1;
    float xs = (bx1 + gx * (bx2 - bx1)) * Hm1;
    float y0f = floorf(ys), x0f = floorf(xs);
    float ly = ys - y0f, lx = xs - x0f;
    int iy0 = (int)fminf(fmaxf(y0f,       0.f), Hm1);
    int iy1 = (int)fminf(fmaxf(y0f + 1.f, 0.f), Hm1);
    int ix0 = (int)fminf(fmaxf(x0f,       0.f), Hm1);
    int ix1 = (int)fminf(fmaxf(x0f + 1.f, 0.f), Hm1);

    const float* fc = f + (size_t)c * H * H;
    float v00 = fc[iy0 * H + ix0];
    float v01 = fc[iy0 * H + ix1];
    float v10 = fc[iy1 * H + ix0];
    float v11 = fc[iy1 * H + ix1];
    float wy0 = 1.f - ly, wy1 = ly, wx0 = 1.f - lx, wx1 = lx;
    float val = v00 * wy0 * wx0 + v01 * wy0 * wx1 + v10 * wy1 * wx0 + v11 * wy1 * wx1;
    bool valid = (ys >= 0.f) && (ys <= Hm1) && (xs >= 0.f) && (xs <= Hm1);
    ph[idx] = (_Float16)(valid ? val : 0.f);
}

// fp32 -> fp16, 4 elems/thread
__global__ __launch_bounds__(256) void cvt16_k(
    const float* __restrict__ src, _Float16* __restrict__ dst, int n4)
{
    int i = blockIdx.x * 256 + threadIdx.x;
    if (i >= n4) return;
    float4 v = ((const float4*)src)[i];
    f16x4 h;
    h.x = (_Float16)v.x; h.y = (_Float16)v.y;
    h.z = (_Float16)v.z; h.w = (_Float16)v.w;
    ((f16x4*)dst)[i] = h;
}

// fused cvt of conv2_w -> w2h, cls_w -> wcat[0:81], box_w -> wcat[81:405]
__global__ __launch_bounds__(256) void cvt3_k(
    const float* __restrict__ w2, const float* __restrict__ cls,
    const float* __restrict__ box, _Float16* __restrict__ w2h,
    _Float16* __restrict__ wcat)
{
    int i = blockIdx.x * 256 + threadIdx.x;
    const int n_w2 = 262144, n_cls = 20736, n_box = 82944;  // float4 units
    const float* src; _Float16* dst; int j;
    if (i < n_w2)               { src = w2;  dst = w2h;                 j = i; }
    else if (i < n_w2 + n_cls)  { src = cls; dst = wcat;                j = i - n_w2; }
    else if (i < n_w2 + n_cls + n_box) { src = box; dst = wcat + 81 * 1024; j = i - n_w2 - n_cls; }
    else return;
    float4 v = ((const float4*)src)[j];
    f16x4 h;
    h.x = (_Float16)v.x; h.y = (_Float16)v.y;
    h.z = (_Float16)v.z; h.w = (_Float16)v.w;
    ((f16x4*)dst)[j] = h;
}

// out[idx] = bias[idx & 1023]  (1M elems)
__global__ __launch_bounds__(256) void init_bias_k(
    const float* __restrict__ bias, float* __restrict__ out)
{
    int idx = blockIdx.x * 256 + threadIdx.x;
    out[idx] = bias[idx & 1023];
}

// hcat init: col<81 -> cls_b, col<405 -> box_b, else 0  (1024x512)
__global__ __launch_bounds__(256) void init_hcat_k(
    const float* __restrict__ cls_b, const float* __restrict__ box_b,
    float* __restrict__ hcat)
{
    int idx = blockIdx.x * 256 + threadIdx.x;
    if (idx >= 1024 * 512) return;
    int col = idx & 511;
    float v = 0.f;
    if (col < 81) v = cls_b[col];
    else if (col < 405) v = box_b[col - 81];
    hcat[idx] = v;
}

// ---------------------------------------------------------------------------
// fp16 MFMA GEMM: C += Ah * Bh^T, atomic fp32 accumulate, XOR-swizzled LDS.
// 128x128 tile, 4 waves (2x2 of 64x64), BK=32, split-K over grid.y.
// M multiple of 128; Bh must have >= ceil(N/128)*128 valid-to-read rows.
// ---------------------------------------------------------------------------
__global__ __launch_bounds__(256) void gemm16h(
    const _Float16* __restrict__ Ah, const _Float16* __restrict__ Bh,
    float* __restrict__ C, int Nn, int lda, int ldb, int kChunk, int tilesN)
{
    __shared__ _Float16 sA[128][32];
    __shared__ _Float16 sB[128][32];

    const int tid  = threadIdx.x;
    const int lane = tid & 63;
    const int wave = tid >> 6;
    const int tm0  = (blockIdx.x / tilesN) * 128;
    const int tn0  = (blockIdx.x % tilesN) * 128;
    const int k0   = blockIdx.y * kChunk;

    const int wm = (wave >> 1) * 64;
    const int wn = (wave & 1) * 64;

    // staging: wave stages LDS rows [wave*32, wave*32+32)
    const int srow = wave * 32 + (lane >> 2);
    // XOR swizzle: physical group (lane&3) holds source group (lane&3)^((row>>1)&3)
    const int skh  = (((lane & 3) ^ ((srow >> 1) & 3)) * 8);   // halfs

    f32x4 acc[4][4];
    #pragma unroll
    for (int i = 0; i < 4; i++)
        #pragma unroll
        for (int j = 0; j < 4; j++) acc[i][j] = (f32x4){0.f, 0.f, 0.f, 0.f};

    const int mrow = wm + (lane & 15);
    const int ncol = wn + (lane & 15);
    // read-side swizzle (period-8 in row, so +16 row offsets share it)
    const int ga = (((lane >> 4) ^ ((mrow >> 1) & 3)) * 8);
    const int gb = (((lane >> 4) ^ ((ncol >> 1) & 3)) * 8);

    for (int kt = 0; kt < kChunk; kt += 32) {
        const size_t ka = (size_t)(tm0 + srow) * lda + k0 + kt + skh;
        const size_t kb = (size_t)(tn0 + srow) * ldb + k0 + kt + skh;
        gload16(Ah + ka,            &sA[wave * 32][0]);
        gload16(Ah + ka + 16 * lda, &sA[wave * 32 + 16][0]);
        gload16(Bh + kb,            &sB[wave * 32][0]);
        gload16(Bh + kb + 16 * ldb, &sB[wave * 32 + 16][0]);
        __syncthreads();

        f16x8 fa[4], fb[4];
        #pragma unroll
        for (int t = 0; t < 4; t++) {
            fa[t] = *(const f16x8*)&sA[mrow + t * 16][ga];
            fb[t] = *(const f16x8*)&sB[ncol + t * 16][gb];
        }
        #pragma unroll
        for (int i = 0; i < 4; i++)
            #pragma unroll
            for (int j = 0; j < 4; j++)
                acc[i][j] = __builtin_amdgcn_mfma_f32_16x16x32_f16(fa[i], fb[j], acc[i][j], 0, 0, 0);
        __syncthreads();
    }

    // C/D layout: col = lane&15, row = (lane>>4)*4 + reg
    const int crow = tm0 + wm + (lane >> 4) * 4;
    const int ccol = tn0 + wn + (lane & 15);
    #pragma unroll
    for (int i = 0; i < 4; i++)
        #pragma unroll
        for (int j = 0; j < 4; j++) {
            float* cp = C + (size_t)(crow + i * 16) * Nn + (ccol + j * 16);
            #pragma unroll
            for (int rg = 0; rg < 4; rg++)
                unsafeAtomicAdd(cp + (size_t)rg * Nn, acc[i][j][rg]);
        }
}

// ---------------------------------------------------------------------------
// fp32 tiled GEMM (tf path): C = A * B^T, split-K partials
// ---------------------------------------------------------------------------
template<int BM, int BN, int TM, int TN>
__global__ __launch_bounds__(256) void gemm_nt(
    const float* __restrict__ A, const float* __restrict__ B,
    float* __restrict__ Cpart,
    int Mm, int Nn, int lda, int ldb, int kChunk, int tilesN)
{
    constexpr int BK = 16;
    __shared__ float As[BK][BM + 4];
    __shared__ float Bs[BK][BN + 4];

    const int tile = blockIdx.x;
    const int s    = blockIdx.y;
    const int tm0  = (tile / tilesN) * BM;
    const int tn0  = (tile % tilesN) * BN;
    const int k0   = s * kChunk;
    const int tid  = threadIdx.x;
    const int tx   = tid % (BN / TN);
    const int ty   = tid / (BN / TN);

    constexpr int AVEC = BM * BK / (256 * 4);
    constexpr int BVEC = BN * BK / (256 * 4);
    const int lrow = tid >> 2;
    const int lkq  = (tid & 3) * 4;

    float acc[TM][TN];
    #pragma unroll
    for (int i = 0; i < TM; i++)
        #pragma unroll
        for (int j = 0; j < TN; j++) acc[i][j] = 0.f;

    for (int kt = 0; kt < kChunk; kt += BK) {
        #pragma unroll
        for (int v = 0; v < AVEC; v++) {
            int row = lrow + v * 64;
            int gm = tm0 + row;
            float4 val = make_float4(0.f, 0.f, 0.f, 0.f);
            if (gm < Mm) val = *(const float4*)&A[(size_t)gm * lda + k0 + kt + lkq];
            As[lkq + 0][row] = val.x; As[lkq + 1][row] = val.y;
            As[lkq + 2][row] = val.z; As[lkq + 3][row] = val.w;
        }
        #pragma unroll
        for (int v = 0; v < BVEC; v++) {
            int row = lrow + v * 64;
            int gn = tn0 + row;
            float4 val = make_float4(0.f, 0.f, 0.f, 0.f);
            if (gn < Nn) val = *(const float4*)&B[(size_t)gn * ldb + k0 + kt + lkq];
            Bs[lkq + 0][row] = val.x; Bs[lkq + 1][row] = val.y;
            Bs[lkq + 2][row] = val.z; Bs[lkq + 3][row] = val.w;
        }
        __syncthreads();
        #pragma unroll
        for (int kk = 0; kk < BK; kk++) {
            float a[TM], b[TN];
            #pragma unroll
            for (int i = 0; i < TM; i++) a[i] = As[kk][ty * TM + i];
            #pragma unroll
            for (int j = 0; j < TN; j++) b[j] = Bs[kk][tx * TN + j];
            #pragma unroll
            for (int i = 0; i < TM; i++)
                #pragma unroll
                for (int j = 0; j < TN; j++)
                    acc[i][j] += a[i] * b[j];
        }
        __syncthreads();
    }

    float* Cs = Cpart + (size_t)s * Mm * Nn;
    #pragma unroll
    for (int i = 0; i < TM; i++) {
        int gm = tm0 + ty * TM + i;
        if (gm >= Mm) continue;
        #pragma unroll
        for (int j = 0; j < TN; j++) {
            int gn = tn0 + tx * TN + j;
            if (gn < Nn) Cs[(size_t)gm * Nn + gn] = acc[i][j];
        }
    }
}

__global__ __launch_bounds__(256) void combine_k(
    const float* __restrict__ part, const float* __restrict__ bias,
    float* __restrict__ out, int MN, int Nn, int nSplit, int act)
{
    int idx = blockIdx.x * 256 + threadIdx.x;
    if (idx >= MN) return;
    float s = 0.f;
    for (int p = 0; p < nSplit; p++) s += part[(size_t)p * MN + idx];
    s += bias[idx % Nn];
    if (act == 1) s = (s >= 0.f) ? s : 0.01f * s;
    out[idx] = s;
}

// ---------------------------------------------------------------------------
// batch-norm over axis 0 of (1024, 1024): 64 row-groups of 16
// ---------------------------------------------------------------------------
__global__ __launch_bounds__(256) void bn_partial(
    const float* __restrict__ h, float* __restrict__ psum, float* __restrict__ psq)
{
    int col = blockIdx.x * 256 + threadIdx.x;   // gridDim.x = 4
    int r0  = blockIdx.y * 16;                  // gridDim.y = 64
    float s = 0.f, q = 0.f;
    for (int r = 0; r < 16; r++) {
        float v = h[(size_t)(r0 + r) * 1024 + col];
        s += v; q += v * v;
    }
    psum[blockIdx.y * 1024 + col] = s;
    psq [blockIdx.y * 1024 + col] = q;
}

__global__ __launch_bounds__(256) void bn_finalize(
    const float* __restrict__ psum, const float* __restrict__ psq,
    const float* __restrict__ g, const float* __restrict__ b,
    float* __restrict__ scale, float* __restrict__ shift)
{
    int col = blockIdx.x * 256 + threadIdx.x;   // gridDim.x = 4
    float s = 0.f, q = 0.f;
    for (int p = 0; p < 64; p++) { s += psum[p * 1024 + col]; q += psq[p * 1024 + col]; }
    float mean = s * (1.f / 1024.f);
    float var  = q * (1.f / 1024.f) - mean * mean;
    float sc = (1.f / sqrtf(var + 0.001f)) * g[col];
    scale[col] = sc;
    shift[col] = b[col] - mean * sc;
}

// bn+relu -> fp16; optionally re-init h in place with next bias (fused)
__global__ __launch_bounds__(256) void bn_apply_relu16(
    float* __restrict__ h, const float* __restrict__ scale,
    const float* __restrict__ shift, _Float16* __restrict__ o16,
    const float* __restrict__ nextBias)   // may be null
{
    int idx = blockIdx.x * 256 + threadIdx.x;
    int col = idx & 1023;
    float v = fmaxf(h[idx] * scale[col] + shift[col], 0.f);
    o16[idx] = (_Float16)v;
    if (nextBias) h[idx] = nextBias[col];
}

// route hcat -> logits / bbox  (grid: (2, 1024), block 256)
__global__ __launch_bounds__(256) void head_finish(
    const float* __restrict__ hcat, float* __restrict__ o_logits,
    float* __restrict__ o_bbox)
{
    int col = blockIdx.x * 256 + threadIdx.x;
    int row = blockIdx.y;
    if (col >= 405) return;
    float v = hcat[(size_t)row * 512 + col];
    if (col < 81) o_logits[(size_t)row * 81 + col] = v;
    else          o_bbox[(size_t)row * 324 + (col - 81)] = v;
}

__global__ __launch_bounds__(64) void softmax81(
    const float* __restrict__ logits, float* __restrict__ probs)
{
    int row = blockIdx.x;
    int lane = threadIdx.x;
    const float* L = logits + (size_t)row * 81;
    float v0 = L[lane];
    float v1 = (lane + 64 < 81) ? L[lane + 64] : -INFINITY;
    float m = fmaxf(v0, v1);
    for (int o = 32; o; o >>= 1) m = fmaxf(m, __shfl_xor(m, o));
    float e0 = expf(v0 - m);
    float e1 = (lane + 64 < 81) ? expf(v1 - m) : 0.f;
    float s = e0 + e1;
    for (int o = 32; o; o >>= 1) s += __shfl_xor(s, o);
    probs[(size_t)row * 81 + lane] = e0 / s;
    if (lane + 64 < 81) probs[(size_t)row * 81 + lane + 64] = e1 / s;
}

// ---------------------------------------------------------------------------
extern "C" void kernel_launch(void* const* d_in, const int* in_sizes, int n_in,
                              void* d_out, int out_size, void* d_ws, size_t ws_size,
                              hipStream_t stream)
{
    const float* p2      = (const float*)d_in[0];
    const float* p3      = (const float*)d_in[1];
    const float* p4      = (const float*)d_in[2];
    const float* p5      = (const float*)d_in[3];
    const float* rois    = (const float*)d_in[4];
    const float* conv1_w = (const float*)d_in[5];
    const float* conv1_b = (const float*)d_in[6];
    const float* bn1_g   = (const float*)d_in[7];
    const float* bn1_b   = (const float*)d_in[8];
    const float* conv2_w = (const float*)d_in[9];
    const float* conv2_b = (const float*)d_in[10];
    const float* bn2_g   = (const float*)d_in[11];
    const float* bn2_b   = (const float*)d_in[12];
    const float* cls_w   = (const float*)d_in[13];
    const float* cls_b   = (const float*)d_in[14];
    const float* box_w   = (const float*)d_in[15];
    const float* box_b   = (const float*)d_in[16];
    const float* tf1_w   = (const float*)d_in[17];
    const float* tf1_b   = (const float*)d_in[18];
    const float* tf2_w   = (const float*)d_in[19];
    const float* tf2_b   = (const float*)d_in[20];

    char* wsb = (char*)d_ws;
    float* out = (float*)d_out;

    _Float16* ph   = (_Float16*)(wsb + PH_OFF);
    _Float16* w1h  = (_Float16*)(wsb + W1_OFF);
    float*    h1   = (float*)(wsb + H1_OFF);
    _Float16* s1h  = (_Float16*)(wsb + S1H_OFF);
    _Float16* s2h  = (_Float16*)(wsb + S2H_OFF);
    _Float16* w2h  = (_Float16*)(wsb + W2H_OFF);
    _Float16* wcat = (_Float16*)(wsb + WCAT_OFF);
    float*    hcat = (float*)(wsb + HCAT_OFF);
    float*    mw1  = (float*)(wsb + MW1_OFF);
    float*    part = (float*)(wsb + PART_OFF);
    float*    psum = (float*)(wsb + STAT_OFF);
    float*    psq  = psum + 64 * 1024;
    float*    scale = psq + 64 * 1024;
    float*    shift = scale + 1024;

    float* o_logits = out;
    float* o_probs  = out + 82944;
    float* o_bbox   = out + 165888;
    float* o_mw     = out + 497664;

    // 1) w1 -> fp16
    cvt16_k<<<12544, 256, 0, stream>>>(conv1_w, w1h, 12544 * 1024 / 4);

    // 2) ROI align -> ph (1024, 12544) fp16
    roi_pool16_k<<<50176, 256, 0, stream>>>(p2, p3, p4, p5, rois, ph);

    // 3) conv1: h1 = bias ; h1 += ph @ w1h^T   (split-K=14, 896 blocks)
    init_bias_k<<<4096, 256, 0, stream>>>(conv1_b, h1);
    gemm16h<<<dim3(64, 14), 256, 0, stream>>>(ph, w1h, h1, 1024, K1, K1, 896, 8);

    // 4) bn1 + relu -> s1h ; h1 := conv2_b (fused) ; cvt w2/cls/box
    bn_partial<<<dim3(4, 64), 256, 0, stream>>>(h1, psum, psq);
    bn_finalize<<<4, 256, 0, stream>>>(psum, psq, bn1_g, bn1_b, scale, shift);
    bn_apply_relu16<<<4096, 256, 0, stream>>>(h1, scale, shift, s1h, conv2_b);
    cvt3_k<<<1429, 256, 0, stream>>>(conv2_w, cls_w, box_w, w2h, wcat);

    // 5) conv2: h1 += s1h @ w2h^T  (split-K=8, 512 blocks)
    gemm16h<<<dim3(64, 8), 256, 0, stream>>>(s1h, w2h, h1, 1024, 1024, 1024, 128, 8);

    // 6) bn2 + relu -> s2h
    bn_partial<<<dim3(4, 64), 256, 0, stream>>>(h1, psum, psq);
    bn_finalize<<<4, 256, 0, stream>>>(psum, psq, bn2_g, bn2_b, scale, shift);
    bn_apply_relu16<<<4096, 256, 0, stream>>>(h1, scale, shift, s2h, nullptr);

    // 7) head: hcat = [cls_b|box_b|0] ; hcat += s2h @ wcat^T (N padded 512)
    init_hcat_k<<<2048, 256, 0, stream>>>(cls_b, box_b, hcat);
    gemm16h<<<dim3(32, 8), 256, 0, stream>>>(s2h, wcat, hcat, 512, 1024, 1024, 128, 4);
    head_finish<<<dim3(2, 1024), 256, 0, stream>>>(hcat, o_logits, o_bbox);

    // 8) probs
    softmax81<<<1024, 64, 0, stream>>>(o_logits, o_probs);

    // 9) mw1 = leaky(cls_w @ tf1_w^T + tf1_b)
    gemm_nt<64, 64, 4, 4><<<dim3(32, 4), 256, 0, stream>>>(
        cls_w, tf1_w, part, 81, 1024, 1024, 1024, 256, 16);
    combine_k<<<(82944 + 255) / 256, 256, 0, stream>>>(part, tf1_b, mw1, 82944, 1024, 4, 1);

    // 10) mw = leaky(mw1 @ tf2_w^T + tf2_b)
    gemm_nt<64, 64, 4, 4><<<dim3(8, 8), 256, 0, stream>>>(
        mw1, tf2_w, part, 81, 256, 1024, 1024, 128, 4);
    combine_k<<<(20736 + 255) / 256, 256, 0, stream>>>(part, tf2_b, o_mw, 20736, 256, 8, 1);
}

// Round 4
// 463.876 us; speedup vs baseline: 1.8440x; 1.1053x over previous
//
#include <hip/hip_runtime.h>
#include <math.h>

// B=2, N=512, C=256, POOL=7, NC=81, IMG=1024 ; M = 1024 rois, K1 = 12544
static constexpr int K1 = 12544;

typedef __attribute__((ext_vector_type(8))) _Float16 f16x8;
typedef __attribute__((ext_vector_type(4))) _Float16 f16x4;
typedef __attribute__((ext_vector_type(4))) float f32x4;

// ---------------- ws layout (byte offsets) ----------------
// REG0 (25.69MB): ph during conv1; small buffers after conv1 completes.
static constexpr size_t REG0_OFF = 0;
static constexpr size_t W1_OFF   = 25690112;   // 25.69 MB fp16 w1
static constexpr size_t PART_OFF = 51380224;   // 32 MB split-K partials
static constexpr size_t H1_OFF   = 84934656;   // 4 MB fp32
// inside REG0, valid only after conv1 gemm has consumed ph:
static constexpr size_t S1H_OFF  = 0;          // 2 MB fp16
static constexpr size_t S2H_OFF  = 2097152;    // 2 MB fp16
static constexpr size_t W2H_OFF  = 4194304;    // 2 MB fp16
static constexpr size_t WCAT_OFF = 6291456;    // 1 MB fp16 (512x1024)
static constexpr size_t MW1_OFF  = 7340032;    // 0.33 MB fp32
static constexpr size_t STAT_OFF = 7671808;    // bn stats

// ---------------------------------------------------------------------------
__device__ __forceinline__ void gload16(const void* g, void* l) {
    __builtin_amdgcn_global_load_lds(
        (const __attribute__((address_space(1))) void*)g,
        (__attribute__((address_space(3))) void*)l, 16, 0, 0);
}

// ---------------------------------------------------------------------------
// prep: blocks [0,50176) ROI-align -> ph fp16 ; blocks [50176,62720) cvt w1
// ---------------------------------------------------------------------------
__global__ __launch_bounds__(256) void prep_k(
    const float* __restrict__ p2, const float* __restrict__ p3,
    const float* __restrict__ p4, const float* __restrict__ p5,
    const float* __restrict__ rois, _Float16* __restrict__ ph,
    const float* __restrict__ w1, _Float16* __restrict__ w1h)
{
    if (blockIdx.x >= 50176) {
        int i = (blockIdx.x - 50176) * 256 + threadIdx.x;   // < 3211264
        float4 v = ((const float4*)w1)[i];
        f16x4 h;
        h.x = (_Float16)v.x; h.y = (_Float16)v.y;
        h.z = (_Float16)v.z; h.w = (_Float16)v.w;
        ((f16x4*)w1h)[i] = h;
        return;
    }
    int idx = blockIdx.x * 256 + threadIdx.x;
    int px = idx % 7;
    int py = (idx / 7) % 7;
    int c  = (idx / 49) & 255;
    int n  = idx / (49 * 256);

    float4 r = ((const float4*)rois)[n];   // (x1, y1, x2, y2)
    float area = (r.w - r.y) * (r.z - r.x);
    float lf = rintf(log2f(sqrtf(area) / 224.f)) + 4.f;
    float lv = fminf(fmaxf(lf, 2.f), 5.f);
    int li = (int)lv;

    const float* f; int H;
    if (li <= 2)      { f = p2; H = 256; }
    else if (li == 3) { f = p3; H = 128; }
    else if (li == 4) { f = p4; H = 64; }
    else              { f = p5; H = 32; }

    const float inv = 1.f / 1024.f;
    float by1 = r.y * inv, bx1 = r.x * inv, by2 = r.w * inv, bx2 = r.z * inv;
    float Hm1 = (float)(H - 1);
    float gy = (float)py / 6.f;
    float gx = (float)px / 6.f;
    float ys = (by1 + gy * (by2 - by1)) * Hm1;
    float xs = (bx1 + gx * (bx2 - bx1)) * Hm1;
    float y0f = floorf(ys), x0f = floorf(xs);
    float ly = ys - y0f, lx = xs - x0f;
    int iy0 = (int)fminf(fmaxf(y0f,       0.f), Hm1);
    int iy1 = (int)fminf(fmaxf(y0f + 1.f, 0.f), Hm1);
    int ix0 = (int)fminf(fmaxf(x0f,       0.f), Hm1);
    int ix1 = (int)fminf(fmaxf(x0f + 1.f, 0.f), Hm1);

    const float* fc = f + (size_t)c * H * H;
    float v00 = fc[iy0 * H + ix0];
    float v01 = fc[iy0 * H + ix1];
    float v10 = fc[iy1 * H + ix0];
    float v11 = fc[iy1 * H + ix1];
    float wy0 = 1.f - ly, wy1 = ly, wx0 = 1.f - lx, wx1 = lx;
    float val = v00 * wy0 * wx0 + v01 * wy0 * wx1 + v10 * wy1 * wx0 + v11 * wy1 * wx1;
    bool valid = (ys >= 0.f) && (ys <= Hm1) && (xs >= 0.f) && (xs <= Hm1);
    ph[idx] = (_Float16)(valid ? val : 0.f);
}

// ---------------------------------------------------------------------------
// fp16 MFMA GEMM: Cpart[s] = Ah * Bh^T (per-split chunk), plain stores.
// 128x128 tile, 4 waves (2x2 of 64x64), BK=32, XOR-swizzled LDS.
// M = 1024 fixed. grid (tilesM*tilesN, nSplit).
// ---------------------------------------------------------------------------
__global__ __launch_bounds__(256) void gemm16h(
    const _Float16* __restrict__ Ah, const _Float16* __restrict__ Bh,
    float* __restrict__ Cpart, int Nn, int lda, int ldb, int kChunk, int tilesN)
{
    __shared__ _Float16 sA[128][32];
    __shared__ _Float16 sB[128][32];

    const int tid  = threadIdx.x;
    const int lane = tid & 63;
    const int wave = tid >> 6;
    const int tm0  = (blockIdx.x / tilesN) * 128;
    const int tn0  = (blockIdx.x % tilesN) * 128;
    const int k0   = blockIdx.y * kChunk;

    const int wm = (wave >> 1) * 64;
    const int wn = (wave & 1) * 64;

    const int srow = wave * 32 + (lane >> 2);
    const int skh  = (((lane & 3) ^ ((srow >> 1) & 3)) * 8);   // halfs

    f32x4 acc[4][4];
    #pragma unroll
    for (int i = 0; i < 4; i++)
        #pragma unroll
        for (int j = 0; j < 4; j++) acc[i][j] = (f32x4){0.f, 0.f, 0.f, 0.f};

    const int mrow = wm + (lane & 15);
    const int ncol = wn + (lane & 15);
    const int ga = (((lane >> 4) ^ ((mrow >> 1) & 3)) * 8);
    const int gb = (((lane >> 4) ^ ((ncol >> 1) & 3)) * 8);

    for (int kt = 0; kt < kChunk; kt += 32) {
        const size_t ka = (size_t)(tm0 + srow) * lda + k0 + kt + skh;
        const size_t kb = (size_t)(tn0 + srow) * ldb + k0 + kt + skh;
        gload16(Ah + ka,            &sA[wave * 32][0]);
        gload16(Ah + ka + 16 * lda, &sA[wave * 32 + 16][0]);
        gload16(Bh + kb,            &sB[wave * 32][0]);
        gload16(Bh + kb + 16 * ldb, &sB[wave * 32 + 16][0]);
        __syncthreads();

        f16x8 fa[4], fb[4];
        #pragma unroll
        for (int t = 0; t < 4; t++) {
            fa[t] = *(const f16x8*)&sA[mrow + t * 16][ga];
            fb[t] = *(const f16x8*)&sB[ncol + t * 16][gb];
        }
        #pragma unroll
        for (int i = 0; i < 4; i++)
            #pragma unroll
            for (int j = 0; j < 4; j++)
                acc[i][j] = __builtin_amdgcn_mfma_f32_16x16x32_f16(fa[i], fb[j], acc[i][j], 0, 0, 0);
        __syncthreads();
    }

    // C/D layout: col = lane&15, row = (lane>>4)*4 + reg
    float* Cs = Cpart + (size_t)blockIdx.y * 1024 * Nn;
    const int crow = tm0 + wm + (lane >> 4) * 4;
    const int ccol = tn0 + wn + (lane & 15);
    #pragma unroll
    for (int i = 0; i < 4; i++)
        #pragma unroll
        for (int j = 0; j < 4; j++) {
            float* cp = Cs + (size_t)(crow + i * 16) * Nn + (ccol + j * 16);
            #pragma unroll
            for (int rg = 0; rg < 4; rg++)
                cp[(size_t)rg * Nn] = acc[i][j][rg];
        }
}

// ---------------------------------------------------------------------------
// combine 8 split-K partials -> h1 (1024x1024), fused bn partial sums.
// grid (4 colgroups, 16 rowgroups), 256 thr. Conv biases omitted: bn's
// (h - mean) cancels any per-column constant exactly.
// ---------------------------------------------------------------------------
__global__ __launch_bounds__(256) void combine_bn_k(
    const float* __restrict__ part, float* __restrict__ h1,
    float* __restrict__ psum, float* __restrict__ psq)
{
    int col = blockIdx.x * 256 + threadIdx.x;
    int r0  = blockIdx.y * 64;
    float s = 0.f, q = 0.f;
    for (int r = 0; r < 64; r++) {
        const float* p0 = part + (size_t)(r0 + r) * 1024 + col;
        float v = p0[0];
        #pragma unroll
        for (int p = 1; p < 8; p++) v += p0[(size_t)p * 1048576];
        h1[(size_t)(r0 + r) * 1024 + col] = v;
        s += v; q += v * v;
    }
    psum[blockIdx.y * 1024 + col] = s;
    psq [blockIdx.y * 1024 + col] = q;
}

__global__ __launch_bounds__(256) void bn_finalize(
    const float* __restrict__ psum, const float* __restrict__ psq,
    const float* __restrict__ g, const float* __restrict__ b,
    float* __restrict__ scale, float* __restrict__ shift)
{
    int col = blockIdx.x * 256 + threadIdx.x;   // gridDim.x = 4
    float s = 0.f, q = 0.f;
    #pragma unroll
    for (int p = 0; p < 16; p++) { s += psum[p * 1024 + col]; q += psq[p * 1024 + col]; }
    float mean = s * (1.f / 1024.f);
    float var  = q * (1.f / 1024.f) - mean * mean;
    float sc = (1.f / sqrtf(var + 0.001f)) * g[col];
    scale[col] = sc;
    shift[col] = b[col] - mean * sc;
}

// bn+relu -> fp16 ; blocks >= 4096 optionally convert w2/cls/box -> fp16
__global__ __launch_bounds__(256) void bn_apply_cvt_k(
    const float* __restrict__ h, const float* __restrict__ scale,
    const float* __restrict__ shift, _Float16* __restrict__ o16,
    const float* __restrict__ w2, const float* __restrict__ cls,
    const float* __restrict__ box, _Float16* __restrict__ w2h,
    _Float16* __restrict__ wcat)
{
    if (blockIdx.x >= 4096) {
        int i = (blockIdx.x - 4096) * 256 + threadIdx.x;
        const int n_w2 = 262144, n_cls = 20736, n_box = 82944;  // float4 units
        const float* src; _Float16* dst; int j;
        if (i < n_w2)               { src = w2;  dst = w2h;              j = i; }
        else if (i < n_w2 + n_cls)  { src = cls; dst = wcat;             j = i - n_w2; }
        else if (i < n_w2 + n_cls + n_box) { src = box; dst = wcat + 81 * 1024; j = i - n_w2 - n_cls; }
        else return;
        float4 v = ((const float4*)src)[j];
        f16x4 hh;
        hh.x = (_Float16)v.x; hh.y = (_Float16)v.y;
        hh.z = (_Float16)v.z; hh.w = (_Float16)v.w;
        ((f16x4*)dst)[j] = hh;
        return;
    }
    int idx = blockIdx.x * 256 + threadIdx.x;
    int col = idx & 1023;
    float v = fmaxf(h[idx] * scale[col] + shift[col], 0.f);
    o16[idx] = (_Float16)v;
}

// ---------------------------------------------------------------------------
// head combine: sum 8 partials (1024x512), add cls/box bias, route to
// logits/bbox, and compute softmax -> probs. One wave per row, 4 rows/block.
// ---------------------------------------------------------------------------
__global__ __launch_bounds__(256) void head_combine_k(
    const float* __restrict__ part, const float* __restrict__ cls_b,
    const float* __restrict__ box_b, float* __restrict__ o_logits,
    float* __restrict__ o_probs, float* __restrict__ o_bbox)
{
    int wave = threadIdx.x >> 6, lane = threadIdx.x & 63;
    int row = blockIdx.x * 4 + wave;
    const float* pr = part + (size_t)row * 512;

    // c = lane (always < 81): logits
    float lv0;
    {
        float s = pr[lane];
        #pragma unroll
        for (int p = 1; p < 8; p++) s += pr[(size_t)p * 524288 + lane];
        s += cls_b[lane];
        lv0 = s;
        o_logits[(size_t)row * 81 + lane] = s;
    }
    float lv1 = -INFINITY;
    for (int c = lane + 64; c < 405; c += 64) {
        float s = pr[c];
        #pragma unroll
        for (int p = 1; p < 8; p++) s += pr[(size_t)p * 524288 + c];
        if (c < 81) {
            s += cls_b[c];
            lv1 = s;
            o_logits[(size_t)row * 81 + c] = s;
        } else {
            s += box_b[c - 81];
            o_bbox[(size_t)row * 324 + (c - 81)] = s;
        }
    }
    // softmax over 81 (lane holds lv0; lanes<17 also lv1)
    float m = fmaxf(lv0, lv1);
    for (int o = 32; o; o >>= 1) m = fmaxf(m, __shfl_xor(m, o));
    float e0 = expf(lv0 - m);
    float e1 = (lane < 17) ? expf(lv1 - m) : 0.f;
    float s = e0 + e1;
    for (int o = 32; o; o >>= 1) s += __shfl_xor(s, o);
    float rs = 1.f / s;
    o_probs[(size_t)row * 81 + lane] = e0 * rs;
    if (lane < 17) o_probs[(size_t)row * 81 + lane + 64] = e1 * rs;
}

// ---------------------------------------------------------------------------
// fp32 tiled GEMM (tf path): C = A * B^T, split-K partials
// ---------------------------------------------------------------------------
template<int BM, int BN, int TM, int TN>
__global__ __launch_bounds__(256) void gemm_nt(
    const float* __restrict__ A, const float* __restrict__ B,
    float* __restrict__ Cpart,
    int Mm, int Nn, int lda, int ldb, int kChunk, int tilesN)
{
    constexpr int BK = 16;
    __shared__ float As[BK][BM + 4];
    __shared__ float Bs[BK][BN + 4];

    const int tile = blockIdx.x;
    const int s    = blockIdx.y;
    const int tm0  = (tile / tilesN) * BM;
    const int tn0  = (tile % tilesN) * BN;
    const int k0   = s * kChunk;
    const int tid  = threadIdx.x;
    const int tx   = tid % (BN / TN);
    const int ty   = tid / (BN / TN);

    constexpr int AVEC = BM * BK / (256 * 4);
    constexpr int BVEC = BN * BK / (256 * 4);
    const int lrow = tid >> 2;
    const int lkq  = (tid & 3) * 4;

    float acc[TM][TN];
    #pragma unroll
    for (int i = 0; i < TM; i++)
        #pragma unroll
        for (int j = 0; j < TN; j++) acc[i][j] = 0.f;

    for (int kt = 0; kt < kChunk; kt += BK) {
        #pragma unroll
        for (int v = 0; v < AVEC; v++) {
            int row = lrow + v * 64;
            int gm = tm0 + row;
            float4 val = make_float4(0.f, 0.f, 0.f, 0.f);
            if (gm < Mm) val = *(const float4*)&A[(size_t)gm * lda + k0 + kt + lkq];
            As[lkq + 0][row] = val.x; As[lkq + 1][row] = val.y;
            As[lkq + 2][row] = val.z; As[lkq + 3][row] = val.w;
        }
        #pragma unroll
        for (int v = 0; v < BVEC; v++) {
            int row = lrow + v * 64;
            int gn = tn0 + row;
            float4 val = make_float4(0.f, 0.f, 0.f, 0.f);
            if (gn < Nn) val = *(const float4*)&B[(size_t)gn * ldb + k0 + kt + lkq];
            Bs[lkq + 0][row] = val.x; Bs[lkq + 1][row] = val.y;
            Bs[lkq + 2][row] = val.z; Bs[lkq + 3][row] = val.w;
        }
        __syncthreads();
        #pragma unroll
        for (int kk = 0; kk < BK; kk++) {
            float a[TM], b[TN];
            #pragma unroll
            for (int i = 0; i < TM; i++) a[i] = As[kk][ty * TM + i];
            #pragma unroll
            for (int j = 0; j < TN; j++) b[j] = Bs[kk][tx * TN + j];
            #pragma unroll
            for (int i = 0; i < TM; i++)
                #pragma unroll
                for (int j = 0; j < TN; j++)
                    acc[i][j] += a[i] * b[j];
        }
        __syncthreads();
    }

    float* Cs = Cpart + (size_t)s * Mm * Nn;
    #pragma unroll
    for (int i = 0; i < TM; i++) {
        int gm = tm0 + ty * TM + i;
        if (gm >= Mm) continue;
        #pragma unroll
        for (int j = 0; j < TN; j++) {
            int gn = tn0 + tx * TN + j;
            if (gn < Nn) Cs[(size_t)gm * Nn + gn] = acc[i][j];
        }
    }
}

__global__ __launch_bounds__(256) void combine_k(
    const float* __restrict__ part, const float* __restrict__ bias,
    float* __restrict__ out, int MN, int Nn, int nSplit, int act)
{
    int idx = blockIdx.x * 256 + threadIdx.x;
    if (idx >= MN) return;
    float s = 0.f;
    for (int p = 0; p < nSplit; p++) s += part[(size_t)p * MN + idx];
    s += bias[idx % Nn];
    if (act == 1) s = (s >= 0.f) ? s : 0.01f * s;
    out[idx] = s;
}

// ---------------------------------------------------------------------------
extern "C" void kernel_launch(void* const* d_in, const int* in_sizes, int n_in,
                              void* d_out, int out_size, void* d_ws, size_t ws_size,
                              hipStream_t stream)
{
    const float* p2      = (const float*)d_in[0];
    const float* p3      = (const float*)d_in[1];
    const float* p4      = (const float*)d_in[2];
    const float* p5      = (const float*)d_in[3];
    const float* rois    = (const float*)d_in[4];
    const float* conv1_w = (const float*)d_in[5];
    const float* bn1_g   = (const float*)d_in[7];
    const float* bn1_b   = (const float*)d_in[8];
    const float* conv2_w = (const float*)d_in[9];
    const float* bn2_g   = (const float*)d_in[11];
    const float* bn2_b   = (const float*)d_in[12];
    const float* cls_w   = (const float*)d_in[13];
    const float* cls_b   = (const float*)d_in[14];
    const float* box_w   = (const float*)d_in[15];
    const float* box_b   = (const float*)d_in[16];
    const float* tf1_w   = (const float*)d_in[17];
    const float* tf1_b   = (const float*)d_in[18];
    const float* tf2_w   = (const float*)d_in[19];
    const float* tf2_b   = (const float*)d_in[20];

    char* wsb = (char*)d_ws;
    float* out = (float*)d_out;

    _Float16* ph   = (_Float16*)(wsb + REG0_OFF);
    _Float16* w1h  = (_Float16*)(wsb + W1_OFF);
    float*    part = (float*)(wsb + PART_OFF);
    float*    h1   = (float*)(wsb + H1_OFF);
    _Float16* s1h  = (_Float16*)(wsb + S1H_OFF);
    _Float16* s2h  = (_Float16*)(wsb + S2H_OFF);
    _Float16* w2h  = (_Float16*)(wsb + W2H_OFF);
    _Float16* wcat = (_Float16*)(wsb + WCAT_OFF);
    float*    mw1  = (float*)(wsb + MW1_OFF);
    float*    psum = (float*)(wsb + STAT_OFF);
    float*    psq  = psum + 16 * 1024;
    float*    scale = psq + 16 * 1024;
    float*    shift = scale + 1024;

    float* o_logits = out;
    float* o_probs  = out + 82944;
    float* o_bbox   = out + 165888;
    float* o_mw     = out + 497664;

    // 1) ROI align -> ph ; cvt w1 -> w1h  (fused)
    prep_k<<<62720, 256, 0, stream>>>(p2, p3, p4, p5, rois, ph, conv1_w, w1h);

    // 2) conv1: part[s] = ph @ w1h^T  (split-K=8, kChunk=1568, grid 512)
    gemm16h<<<dim3(64, 8), 256, 0, stream>>>(ph, w1h, part, 1024, K1, K1, 1568, 8);

    // 3) combine + bn1 partial ; finalize ; apply->s1h + cvt w2/cls/box
    combine_bn_k<<<dim3(4, 16), 256, 0, stream>>>(part, h1, psum, psq);
    bn_finalize<<<4, 256, 0, stream>>>(psum, psq, bn1_g, bn1_b, scale, shift);
    bn_apply_cvt_k<<<5525, 256, 0, stream>>>(h1, scale, shift, s1h,
                                             conv2_w, cls_w, box_w, w2h, wcat);

    // 4) conv2: part[s] = s1h @ w2h^T  (split-K=8, kChunk=128)
    gemm16h<<<dim3(64, 8), 256, 0, stream>>>(s1h, w2h, part, 1024, 1024, 1024, 128, 8);

    // 5) combine + bn2 ; apply -> s2h
    combine_bn_k<<<dim3(4, 16), 256, 0, stream>>>(part, h1, psum, psq);
    bn_finalize<<<4, 256, 0, stream>>>(psum, psq, bn2_g, bn2_b, scale, shift);
    bn_apply_cvt_k<<<4096, 256, 0, stream>>>(h1, scale, shift, s2h,
                                             nullptr, nullptr, nullptr, nullptr, nullptr);

    // 6) head: part[s] = s2h @ wcat^T (N=512 padded, split-K=8)
    gemm16h<<<dim3(32, 8), 256, 0, stream>>>(s2h, wcat, part, 512, 1024, 1024, 128, 4);
    head_combine_k<<<256, 256, 0, stream>>>(part, cls_b, box_b, o_logits, o_probs, o_bbox);

    // 7) mw1 = leaky(cls_w @ tf1_w^T + tf1_b)
    gemm_nt<64, 64, 4, 4><<<dim3(32, 4), 256, 0, stream>>>(
        cls_w, tf1_w, part, 81, 1024, 1024, 1024, 256, 16);
    combine_k<<<(82944 + 255) / 256, 256, 0, stream>>>(part, tf1_b, mw1, 82944, 1024, 4, 1);

    // 8) mw = leaky(mw1 @ tf2_w^T + tf2_b)
    gemm_nt<64, 64, 4, 4><<<dim3(8, 8), 256, 0, stream>>>(
        mw1, tf2_w, part, 81, 256, 1024, 1024, 128, 4);
    combine_k<<<(20736 + 255) / 256, 256, 0, stream>>>(part, tf2_b, o_mw, 20736, 256, 8, 1);
}